// Round 6
// baseline (44.505 us; speedup 1.0000x reference)
//
#include <hip/hip_runtime.h>
#include <math.h>

constexpr int T_LEN  = 8192;   // per-row length (== TREF)
constexpr int B_ROWS = 4096;
constexpr int NB     = 49;     // NBINS - 1 bins
constexpr int NC     = 32;     // histogram replicas (copy = tid & 31)
constexpr int HDIM   = 32;
constexpr int FBINS  = 8192;   // fine CDF resolution
constexpr int ROWS   = 4;      // rows per block in the main kernel
constexpr float EPSF = 1e-10f;

// ws layout (float units): [0]=rmin [1]=rmax ; int cdf[FBINS+1] at +8 ;
// float binned[T_LEN] (counting-scattered ref) at +8208
constexpr int WS_CDF_OFF    = 8;
constexpr int WS_BINNED_OFF = 8208;

// LDS pad: +1 word per 32 so per-thread 32-contiguous chunks are conflict-free
#define HP(i) ((i) + ((i) >> 5))

// LDS-only block sync: waits DS ops, leaves global loads in flight (no vmcnt
// drain). All cross-thread data in the main kernel lives in LDS, so this is
// semantically sufficient. sched_barrier keeps the compiler from hoisting
// post-barrier ops above it (rule #18).
__device__ __forceinline__ void sync_lds() {
    asm volatile("s_waitcnt lgkmcnt(0)" ::: "memory");
    __builtin_amdgcn_s_barrier();
    __builtin_amdgcn_sched_barrier(0);
}

// -------- kernel 1 (1 block): ref min/max + fine histogram + CDF + scatter ----
__global__ __launch_bounds__(256)
void ref_cdf_kernel(const float* __restrict__ ref, float* __restrict__ wsf) {
    __shared__ float sv[FBINS];          // 32 KB ref copy
    __shared__ int   hist[HP(FBINS)];    // padded fine histogram -> excl. scan
    __shared__ int   wsum[4];
    __shared__ float rmn4[4], rmx4[4];
    const int tid  = threadIdx.x;
    const int lane = tid & 63;
    const int wave = tid >> 6;

    const float4* r4 = (const float4*)ref;
    float4* sv4 = (float4*)sv;
    float mn = 3.0e38f, mx = -3.0e38f;
    #pragma unroll
    for (int i = 0; i < 8; ++i) {
        float4 v = r4[tid + i * 256];
        sv4[tid + i * 256] = v;
        mn = fminf(mn, fminf(fminf(v.x, v.y), fminf(v.z, v.w)));
        mx = fmaxf(mx, fmaxf(fmaxf(v.x, v.y), fmaxf(v.z, v.w)));
    }
    for (int i = tid; i < HP(FBINS); i += 256) hist[i] = 0;
    #pragma unroll
    for (int off = 32; off > 0; off >>= 1) {
        mn = fminf(mn, __shfl_xor(mn, off));
        mx = fmaxf(mx, __shfl_xor(mx, off));
    }
    if (lane == 0) { rmn4[wave] = mn; rmx4[wave] = mx; }
    __syncthreads();
    const float rmin = fminf(fminf(rmn4[0], rmn4[1]), fminf(rmn4[2], rmn4[3]));
    const float rmax = fmaxf(fmaxf(rmx4[0], rmx4[1]), fmaxf(rmx4[2], rmx4[3]));
    const float finv = (float)FBINS / (rmax - rmin);

    // fine histogram ((x-rmin)*finv >= 0 -> trunc == floor)
    for (int i = tid; i < FBINS; i += 256) {
        int fb = min(max((int)((sv[i] - rmin) * finv), 0), FBINS - 1);
        atomicAdd(&hist[HP(fb)], 1);
    }
    __syncthreads();

    // exclusive scan: per-thread 32-chunk (padded, conflict-free) + wave
    // shuffle-scan + tiny cross-wave prefix. 2 barriers total.
    const int base = tid * 32;
    int s = 0;
    #pragma unroll
    for (int j = 0; j < 32; ++j) {
        int h = hist[HP(base + j)]; hist[HP(base + j)] = s; s += h;
    }
    const int own = s;
    int incl = s;
    #pragma unroll
    for (int off = 1; off < 64; off <<= 1) {
        int t = __shfl_up(incl, off);
        if (lane >= off) incl += t;
    }
    if (lane == 63) wsum[wave] = incl;
    __syncthreads();
    int woff = 0;
    #pragma unroll
    for (int w = 0; w < 4; ++w) if (w < wave) woff += wsum[w];
    const int add = woff + incl - own;
    #pragma unroll
    for (int j = 0; j < 32; ++j) hist[HP(base + j)] += add;
    __syncthreads();

    // publish pristine CDF, then scatter (hist doubles as running counters)
    int* cdf = (int*)(wsf + WS_CDF_OFF);
    for (int i = tid; i < FBINS; i += 256) cdf[i] = hist[HP(i)];
    if (tid == 0) { cdf[FBINS] = T_LEN; wsf[0] = rmin; wsf[1] = rmax; }
    __syncthreads();

    float* binned = wsf + WS_BINNED_OFF;
    for (int i = tid; i < FBINS; i += 256) {
        float x = sv[i];
        int fb = min(max((int)((x - rmin) * finv), 0), FBINS - 1);
        int pos = atomicAdd(&hist[HP(fb)], 1);
        binned[pos] = x;
    }
}

// ---------------- kernel 2: pipelined per-row KL + batched tails + MLP -------
// 1024 blocks x 4 rows. Rows double-buffered in registers; next row's loads
// are issued before this row's compute and survive the (LDS-only) barriers.
// After all 4 rows, each of the 4 waves runs one row's tail in parallel.
__global__ __launch_bounds__(256)
void kl_main_kernel(const float* __restrict__ cur,
                    const float* __restrict__ wsf,
                    const float* __restrict__ w1,
                    const float* __restrict__ b1,
                    const float* __restrict__ w2,
                    const float* __restrict__ b2,
                    float* __restrict__ kl_out,
                    float* __restrict__ enc_out) {
    __shared__ unsigned hq[NC * NB];
    __shared__ float rmnS[4], rmxS[4];
    __shared__ unsigned hrow[ROWS][NB];
    __shared__ float metaLo[ROWS], metaW[ROWS];

    const int tid  = threadIdx.x;
    const int lane = tid & 63;
    const int wave = tid >> 6;
    const int rbase = blockIdx.x * ROWS;
    const float4* src = (const float4*)(cur + (size_t)rbase * T_LEN);

    for (int i = tid; i < NC * NB; i += 256) hq[i] = 0u;
    const float rmin = wsf[0], rmax = wsf[1];

    float4 va[8], vb[8];
    #pragma unroll
    for (int i = 0; i < 8; ++i) va[i] = src[tid + i * 256];

#define ROW_STEP(V, VN, R, PF)                                                 \
    {                                                                          \
        if (PF) {                                                              \
            const float4* s2 = src + ((R) + 1) * (T_LEN / 4);                  \
            _Pragma("unroll")                                                  \
            for (int i = 0; i < 8; ++i) VN[i] = s2[tid + i * 256];             \
        }                                                                      \
        float mn = 3.0e38f, mx = -3.0e38f;                                     \
        _Pragma("unroll")                                                      \
        for (int i = 0; i < 8; ++i) {                                          \
            mn = fminf(mn, fminf(fminf(V[i].x, V[i].y), fminf(V[i].z, V[i].w)));\
            mx = fmaxf(mx, fmaxf(fmaxf(V[i].x, V[i].y), fmaxf(V[i].z, V[i].w)));\
        }                                                                      \
        _Pragma("unroll")                                                      \
        for (int off = 32; off > 0; off >>= 1) {                               \
            mn = fminf(mn, __shfl_xor(mn, off));                               \
            mx = fmaxf(mx, __shfl_xor(mx, off));                               \
        }                                                                      \
        if (lane == 0) { rmnS[wave] = mn; rmxS[wave] = mx; }                   \
        sync_lds();                                                            \
        const float lo = fminf(rmin,                                           \
            fminf(fminf(rmnS[0], rmnS[1]), fminf(rmnS[2], rmnS[3])));          \
        const float hi = fmaxf(rmax,                                           \
            fmaxf(fmaxf(rmxS[0], rmxS[1]), fmaxf(rmxS[2], rmxS[3])));          \
        const float width = (hi - lo) / (float)NB;                             \
        const float winv = 1.0f / width, nlw = -lo * winv;                     \
        unsigned* myq = hq + (tid & (NC - 1)) * NB;                            \
        _Pragma("unroll")                                                      \
        for (int i = 0; i < 8; ++i) {                                          \
            int i0 = min(max((int)fmaf(V[i].x, winv, nlw), 0), NB - 1);        \
            int i1 = min(max((int)fmaf(V[i].y, winv, nlw), 0), NB - 1);        \
            int i2 = min(max((int)fmaf(V[i].z, winv, nlw), 0), NB - 1);        \
            int i3 = min(max((int)fmaf(V[i].w, winv, nlw), 0), NB - 1);        \
            atomicAdd(&myq[i0], 1u); atomicAdd(&myq[i1], 1u);                  \
            atomicAdd(&myq[i2], 1u); atomicAdd(&myq[i3], 1u);                  \
        }                                                                      \
        sync_lds();                                                            \
        if (tid < 64 && lane < NB) {                                           \
            unsigned sq = 0;                                                   \
            _Pragma("unroll")                                                  \
            for (int c = 0; c < NC; ++c) sq += hq[c * NB + lane];              \
            hrow[R][lane] = sq;                                                \
        }                                                                      \
        if (tid == 0) { metaLo[R] = lo; metaW[R] = width; }                    \
        sync_lds();                                                            \
        for (int i = tid; i < NC * NB; i += 256) hq[i] = 0u;                   \
    }

    ROW_STEP(va, vb, 0, true)
    ROW_STEP(vb, va, 1, true)
    ROW_STEP(va, vb, 2, true)
    ROW_STEP(vb, va, 3, false)
#undef ROW_STEP

    // ---- batched tails: wave w handles row rbase + w ----
    const int row = rbase + wave;
    const float lo = metaLo[wave], width = metaW[wave];
    const bool act = lane < NB;
    const float inv = 1.0f / ((float)T_LEN * width);
    float p = 0.0f, q = 0.0f;
    if (act) q = (float)hrow[wave][lane] * inv + EPSF;

    // reference cumulative counts C(k) via fine-CDF window + exact predicate
    int C = T_LEN;
    if (lane < NB - 1) {
        const float kp1  = (float)(lane + 1);
        const float finv = (float)FBINS / (rmax - rmin);
        const int* cdf = (const int*)(wsf + WS_CDF_OFF);
        const float* binned = wsf + WS_BINNED_OFF;
        const float t = fmaf(width, kp1, lo);
        int fb = (int)floorf((t - rmin) * finv);
        int a  = min(max(fb - 2, 0), FBINS);
        int bb = min(max(fb + 3, 0), FBINS);
        int ia = cdf[a], ib = cdf[bb];
        C = ia;
        for (int i = ia; i < ib; i += 4) {
            float x0 = binned[i];
            float x1 = (i + 1 < ib) ? binned[i + 1] : 3.0e38f;
            float x2 = (i + 2 < ib) ? binned[i + 2] : 3.0e38f;
            float x3 = (i + 3 < ib) ? binned[i + 3] : 3.0e38f;
            C += ((x0 - lo) / width < kp1) ? 1 : 0;
            C += ((x1 - lo) / width < kp1) ? 1 : 0;
            C += ((x2 - lo) / width < kp1) ? 1 : 0;
            C += ((x3 - lo) / width < kp1) ? 1 : 0;
        }
    }
    int Cprev = __shfl_up(C, 1);
    if (lane == 0) Cprev = 0;
    if (act) p = (float)(C - Cprev) * inv + EPSF;

    float P = p, Q = q;
    #pragma unroll
    for (int off = 32; off > 0; off >>= 1) {
        P += __shfl_xor(P, off);
        Q += __shfl_xor(Q, off);
    }
    float term = 0.0f;
    if (act) {
        const float pn = p / P;
        const float qn = q / Q;
        term = pn * logf(pn / qn);
    }
    #pragma unroll
    for (int off = 32; off > 0; off >>= 1) term += __shfl_xor(term, off);
    if (lane == 0) kl_out[row] = term;

    if (lane < HDIM) {
        float acc = b2[lane];
        #pragma unroll
        for (int t2 = 0; t2 < HDIM; ++t2) {
            float h = fmaxf(fmaf(term, w1[t2], b1[t2]), 0.0f);
            acc = fmaf(h, w2[lane * HDIM + t2], acc);
        }
        enc_out[(size_t)row * HDIM + lane] = acc;
    }
}

extern "C" void kernel_launch(void* const* d_in, const int* in_sizes, int n_in,
                              void* d_out, int out_size, void* d_ws, size_t ws_size,
                              hipStream_t stream) {
    const float* cur = (const float*)d_in[0];
    const float* ref = (const float*)d_in[1];
    const float* w1  = (const float*)d_in[2];
    const float* b1  = (const float*)d_in[3];
    const float* w2  = (const float*)d_in[4];
    const float* b2  = (const float*)d_in[5];
    float* out = (float*)d_out;           // [0, B) = kl ; [B, B + B*H) = encoded
    float* wsf = (float*)d_ws;

    ref_cdf_kernel<<<1, 256, 0, stream>>>(ref, wsf);
    kl_main_kernel<<<B_ROWS / ROWS, 256, 0, stream>>>(
        cur, wsf, w1, b1, w2, b2, out, out + B_ROWS);
}